// Round 1
// baseline (643.107 us; speedup 1.0000x reference)
//
#include <hip/hip_runtime.h>

typedef __bf16 bf16_t;
typedef __bf16 bf16x4 __attribute__((ext_vector_type(4)));
typedef __bf16 bf16x8 __attribute__((ext_vector_type(8)));
typedef float f32x4 __attribute__((ext_vector_type(4)));

#define LOG2E 1.4426950408889634f

static __device__ __forceinline__ bf16_t f2bf(float f) {
  unsigned u = __builtin_bit_cast(unsigned, f);
  u = (u + 0x7fff + ((u >> 16) & 1)) >> 16;
  unsigned short h = (unsigned short)u;
  return __builtin_bit_cast(bf16_t, h);
}
static __device__ __forceinline__ float bf2f(bf16_t b) {
  unsigned short s = __builtin_bit_cast(unsigned short, b);
  unsigned u = ((unsigned)s) << 16;
  return __builtin_bit_cast(float, u);
}

// ---------------- conversion kernels ----------------
__global__ void cvt_f2b(const float* __restrict__ in, bf16_t* __restrict__ out, int n4) {
  int i = blockIdx.x * blockDim.x + threadIdx.x;
  if (i >= n4) return;
  const float4 f = reinterpret_cast<const float4*>(in)[i];
  bf16x4 o;
  o[0] = f2bf(f.x); o[1] = f2bf(f.y); o[2] = f2bf(f.z); o[3] = f2bf(f.w);
  reinterpret_cast<bf16x4*>(out)[i] = o;
}

__global__ void mask_bias_k(const int* __restrict__ m, bf16_t* __restrict__ out, int n4) {
  int i = blockIdx.x * blockDim.x + threadIdx.x;
  if (i >= n4) return;
  const int4 v = reinterpret_cast<const int4*>(m)[i];
  bf16x4 o;
  o[0] = f2bf(v.x ? 0.f : -1e9f);
  o[1] = f2bf(v.y ? 0.f : -1e9f);
  o[2] = f2bf(v.z ? 0.f : -1e9f);
  o[3] = f2bf(v.w ? 0.f : -1e9f);
  reinterpret_cast<bf16x4*>(out)[i] = o;
}

// ---------------- GEMM: C[m,n] = sum_k A[m,k]*Bw[n,k] + bias[n] ----------------
// A: [8192,1024] bf16 row-major. Bw: [1024,1024] bf16 (torch Linear weight [out,in] == B^T).
// OM=0: bf16 row-major out. OM=1: V-transposed out Vt[(b*1024+n)*2048+s]. OM=2: f32 row-major.
#define GLD_LDS(g, l) \
  __builtin_amdgcn_global_load_lds((const __attribute__((address_space(1))) void*)(g), \
                                   (__attribute__((address_space(3))) void*)(l), 16, 0, 0)

template <int OM>
__global__ __launch_bounds__(256, 2) void gemm_bias(
    const bf16_t* __restrict__ A, const bf16_t* __restrict__ Bw,
    const float* __restrict__ bias, void* __restrict__ Cout) {
  constexpr int K = 1024, N = 1024;
  __shared__ bf16_t As[128 * 32];
  __shared__ bf16_t Bs[128 * 32];
  const int tid = threadIdx.x;
  const int lane = tid & 63;
  const int wave = tid >> 6;
  const int wm = (wave >> 1) * 64, wn = (wave & 1) * 64;
  const int l15 = lane & 15, lhi = lane >> 4;
  const int bm = blockIdx.x, bn = blockIdx.y;
  const int r0 = tid >> 2;          // staging row 0..63
  const int kc = (tid & 3) * 8;     // staging k-chunk
  const bf16_t* ga = A + (size_t)(bm * 128 + r0) * K + kc;
  const bf16_t* gb = Bw + (size_t)(bn * 128 + r0) * K + kc;
  char* ldsA = (char*)As + wave * 1024;
  char* ldsB = (char*)Bs + wave * 1024;
  f32x4 acc[4][4] = {};
  for (int k0 = 0; k0 < K; k0 += 32) {
    __syncthreads();
    GLD_LDS(ga + k0, ldsA);
    GLD_LDS(ga + 64 * K + k0, ldsA + 4096);
    GLD_LDS(gb + k0, ldsB);
    GLD_LDS(gb + 64 * K + k0, ldsB + 4096);
    __syncthreads();
    bf16x8 af[4], bfv[4];
#pragma unroll
    for (int i = 0; i < 4; ++i)
      af[i] = *reinterpret_cast<const bf16x8*>(&As[(wm + i * 16 + l15) * 32 + lhi * 8]);
#pragma unroll
    for (int j = 0; j < 4; ++j)
      bfv[j] = *reinterpret_cast<const bf16x8*>(&Bs[(wn + j * 16 + l15) * 32 + lhi * 8]);
#pragma unroll
    for (int i = 0; i < 4; ++i)
#pragma unroll
      for (int j = 0; j < 4; ++j)
        acc[i][j] = __builtin_amdgcn_mfma_f32_16x16x32_bf16(af[i], bfv[j], acc[i][j], 0, 0, 0);
  }
  // epilogue: C/D layout col=lane&15, row=(lane>>4)*4+reg
#pragma unroll
  for (int i = 0; i < 4; ++i) {
#pragma unroll
    for (int j = 0; j < 4; ++j) {
      int n = bn * 128 + wn + j * 16 + l15;
      float bv = bias[n];
#pragma unroll
      for (int r = 0; r < 4; ++r) {
        int m = bm * 128 + wm + i * 16 + lhi * 4 + r;
        float val = acc[i][j][r] + bv;
        if (OM == 0) {
          ((bf16_t*)Cout)[(size_t)m * N + n] = f2bf(val);
        } else if (OM == 1) {
          int b = m >> 11, s = m & 2047;
          ((bf16_t*)Cout)[((size_t)b * 1024 + n) * 2048 + s] = f2bf(val);
        } else {
          ((float*)Cout)[(size_t)m * N + n] = val;
        }
      }
    }
  }
}

// ---------------- flash attention ----------------
// Qp,Kp: [B*S,1024] bf16 (head h = cols h*64..h*64+63). Vt: [B][1024][2048] bf16.
// maskb: [2048][2048] bf16 additive bias. Xb out: [B*S,1024] bf16.
__global__ __launch_bounds__(256, 2) void attn_kernel(
    const bf16_t* __restrict__ Qp, const bf16_t* __restrict__ Kp,
    const bf16_t* __restrict__ Vt, const bf16_t* __restrict__ maskb,
    bf16_t* __restrict__ Xb) {
  constexpr int S = 2048, D = 1024;
  const int tid = threadIdx.x, wave = tid >> 6, lane = tid & 63;
  const int l15 = lane & 15, lhi = lane >> 4;
  const int blk = blockIdx.x;
  const int qt = blk & 31;   // 32 q-tiles of 64 per (b,h)
  const int bh = blk >> 5;
  const int b = bh >> 4, h = bh & 15;
  const int q0 = qt * 64 + wave * 16;  // q row base (within S) for this wave
  __shared__ bf16_t Plds[4][16 * 32];

  const bf16_t* qrow = Qp + (size_t)(b * S + q0 + l15) * D + h * 64;
  bf16x8 qf0 = *reinterpret_cast<const bf16x8*>(qrow + lhi * 8);
  bf16x8 qf1 = *reinterpret_cast<const bf16x8*>(qrow + 32 + lhi * 8);
  const bf16_t* kb = Kp + (size_t)(b * S) * D + h * 64;
  const bf16_t* vt = Vt + ((size_t)b * 1024 + h * 64) * 2048;
  const bf16_t* mb = maskb + (size_t)(q0 + lhi * 4) * S;

  f32x4 o[4] = {};
  float mreg[4], lsum[4];
#pragma unroll
  for (int r = 0; r < 4; ++r) { mreg[r] = -__builtin_inff(); lsum[r] = 0.f; }

  for (int k0 = 0; k0 < S; k0 += 32) {
    f32x4 s0 = {}, s1 = {};
    {
      const bf16_t* kr0 = kb + (size_t)(k0 + l15) * D;
      const bf16_t* kr1 = kb + (size_t)(k0 + 16 + l15) * D;
      bf16x8 ka = *reinterpret_cast<const bf16x8*>(kr0 + lhi * 8);
      bf16x8 kc_ = *reinterpret_cast<const bf16x8*>(kr0 + 32 + lhi * 8);
      s0 = __builtin_amdgcn_mfma_f32_16x16x32_bf16(qf0, ka, s0, 0, 0, 0);
      s0 = __builtin_amdgcn_mfma_f32_16x16x32_bf16(qf1, kc_, s0, 0, 0, 0);
      ka = *reinterpret_cast<const bf16x8*>(kr1 + lhi * 8);
      kc_ = *reinterpret_cast<const bf16x8*>(kr1 + 32 + lhi * 8);
      s1 = __builtin_amdgcn_mfma_f32_16x16x32_bf16(qf0, ka, s1, 0, 0, 0);
      s1 = __builtin_amdgcn_mfma_f32_16x16x32_bf16(qf1, kc_, s1, 0, 0, 0);
    }
#pragma unroll
    for (int r = 0; r < 4; ++r) {
      float bias0 = bf2f(mb[(size_t)r * S + k0 + l15]);
      float bias1 = bf2f(mb[(size_t)r * S + k0 + 16 + l15]);
      float v0 = s0[r] * 0.125f + bias0;
      float v1 = s1[r] * 0.125f + bias1;
      float mx = fmaxf(v0, v1);
      mx = fmaxf(mx, __shfl_xor(mx, 1, 16));
      mx = fmaxf(mx, __shfl_xor(mx, 2, 16));
      mx = fmaxf(mx, __shfl_xor(mx, 4, 16));
      mx = fmaxf(mx, __shfl_xor(mx, 8, 16));
      float mnew = fmaxf(mreg[r], mx);
      float alpha = __builtin_amdgcn_exp2f((mreg[r] - mnew) * LOG2E);
      float p0 = __builtin_amdgcn_exp2f((v0 - mnew) * LOG2E);
      float p1 = __builtin_amdgcn_exp2f((v1 - mnew) * LOG2E);
      float rs = p0 + p1;
      rs += __shfl_xor(rs, 1, 16);
      rs += __shfl_xor(rs, 2, 16);
      rs += __shfl_xor(rs, 4, 16);
      rs += __shfl_xor(rs, 8, 16);
      lsum[r] = lsum[r] * alpha + rs;
      mreg[r] = mnew;
#pragma unroll
      for (int dt = 0; dt < 4; ++dt) o[dt][r] *= alpha;
      Plds[wave][(lhi * 4 + r) * 32 + l15] = f2bf(p0);
      Plds[wave][(lhi * 4 + r) * 32 + 16 + l15] = f2bf(p1);
    }
    __syncthreads();
    bf16x8 pf = *reinterpret_cast<const bf16x8*>(&Plds[wave][l15 * 32 + lhi * 8]);
#pragma unroll
    for (int dt = 0; dt < 4; ++dt) {
      const bf16_t* vr = vt + (size_t)(dt * 16 + l15) * 2048 + k0 + lhi * 8;
      bf16x8 vf = *reinterpret_cast<const bf16x8*>(vr);
      o[dt] = __builtin_amdgcn_mfma_f32_16x16x32_bf16(pf, vf, o[dt], 0, 0, 0);
    }
    __syncthreads();
  }
  float inv[4];
#pragma unroll
  for (int r = 0; r < 4; ++r) inv[r] = 1.f / lsum[r];
  bf16_t* xout = Xb + (size_t)(b * S + q0 + lhi * 4) * D + h * 64;
#pragma unroll
  for (int dt = 0; dt < 4; ++dt)
#pragma unroll
    for (int r = 0; r < 4; ++r)
      xout[(size_t)r * D + dt * 16 + l15] = f2bf(o[dt][r] * inv[r]);
}

// ---------------- launch ----------------
extern "C" void kernel_launch(void* const* d_in, const int* in_sizes, int n_in,
                              void* d_out, int out_size, void* d_ws, size_t ws_size,
                              hipStream_t stream) {
  const float* q = (const float*)d_in[0];
  const float* k = (const float*)d_in[1];
  const float* v = (const float*)d_in[2];
  const int* mask = (const int*)d_in[3];
  const float* w_q = (const float*)d_in[4];
  const float* b_q = (const float*)d_in[5];
  const float* w_k = (const float*)d_in[6];
  const float* b_k = (const float*)d_in[7];
  const float* w_v = (const float*)d_in[8];
  const float* b_v = (const float*)d_in[9];
  const float* w_o = (const float*)d_in[10];
  const float* b_o = (const float*)d_in[11];

  char* ws = (char*)d_ws;
  const size_t SZ = (size_t)8192 * 1024 * 2;  // 16 MiB per [8192,1024] bf16 array
  bf16_t* qc = (bf16_t*)(ws + 0 * SZ);
  bf16_t* kc = (bf16_t*)(ws + 1 * SZ);
  bf16_t* vc = (bf16_t*)(ws + 2 * SZ);
  bf16_t* Qp = (bf16_t*)(ws + 3 * SZ);
  bf16_t* Kp = (bf16_t*)(ws + 4 * SZ);
  bf16_t* Vt = (bf16_t*)(ws + 5 * SZ);
  bf16_t* Xb = (bf16_t*)(ws + 6 * SZ);
  bf16_t* mbias = (bf16_t*)(ws + 7 * SZ);                 // 8 MiB
  bf16_t* wqb = (bf16_t*)(ws + 7 * SZ + 8388608);
  bf16_t* wkb = wqb + 1048576;
  bf16_t* wvb = wkb + 1048576;
  bf16_t* wob = wvb + 1048576;

  cvt_f2b<<<8192, 256, 0, stream>>>(q, qc, 2097152);
  cvt_f2b<<<8192, 256, 0, stream>>>(k, kc, 2097152);
  cvt_f2b<<<8192, 256, 0, stream>>>(v, vc, 2097152);
  cvt_f2b<<<1024, 256, 0, stream>>>(w_q, wqb, 262144);
  cvt_f2b<<<1024, 256, 0, stream>>>(w_k, wkb, 262144);
  cvt_f2b<<<1024, 256, 0, stream>>>(w_v, wvb, 262144);
  cvt_f2b<<<1024, 256, 0, stream>>>(w_o, wob, 262144);
  mask_bias_k<<<4096, 256, 0, stream>>>(mask, mbias, 1048576);

  dim3 gg(64, 8);
  gemm_bias<0><<<gg, 256, 0, stream>>>(qc, wqb, b_q, Qp);
  gemm_bias<0><<<gg, 256, 0, stream>>>(kc, wkb, b_k, Kp);
  gemm_bias<1><<<gg, 256, 0, stream>>>(vc, wvb, b_v, Vt);
  attn_kernel<<<2048, 256, 0, stream>>>(Qp, Kp, Vt, mbias, Xb);
  gemm_bias<2><<<gg, 256, 0, stream>>>(Xb, wob, b_o, d_out);
}

// Round 2
// 419.764 us; speedup vs baseline: 1.5321x; 1.5321x over previous
//
#include <hip/hip_runtime.h>

typedef __bf16 bf16_t;
typedef __bf16 bf16x4 __attribute__((ext_vector_type(4)));
typedef __bf16 bf16x8 __attribute__((ext_vector_type(8)));
typedef float f32x4 __attribute__((ext_vector_type(4)));
typedef float f32x16 __attribute__((ext_vector_type(16)));
typedef unsigned int uint;
typedef uint uint4v __attribute__((ext_vector_type(4)));

static __device__ __forceinline__ bf16_t f2bf(float f) {
  unsigned u = __builtin_bit_cast(unsigned, f);
  u = (u + 0x7fff + ((u >> 16) & 1)) >> 16;
  unsigned short h = (unsigned short)u;
  return __builtin_bit_cast(bf16_t, h);
}
static __device__ __forceinline__ float bf2f(bf16_t b) {
  unsigned short s = __builtin_bit_cast(unsigned short, b);
  unsigned u = ((unsigned)s) << 16;
  return __builtin_bit_cast(float, u);
}
static __device__ __forceinline__ uint pack2(float a, float b) {
  uint lo = __builtin_bit_cast(unsigned short, (bf16_t)a);
  uint hi = __builtin_bit_cast(unsigned short, (bf16_t)b);
  return lo | (hi << 16);
}

// ---------------- conversion kernels ----------------
__global__ void cvt_f2b(const float* __restrict__ in, bf16_t* __restrict__ out, int n4) {
  int i = blockIdx.x * blockDim.x + threadIdx.x;
  if (i >= n4) return;
  const float4 f = reinterpret_cast<const float4*>(in)[i];
  bf16x4 o;
  o[0] = f2bf(f.x); o[1] = f2bf(f.y); o[2] = f2bf(f.z); o[3] = f2bf(f.w);
  reinterpret_cast<bf16x4*>(out)[i] = o;
}

// mask permuted into 32x32 MFMA C-layout register order:
// out[t][q][h][r] (t=k0/32, q=0..2047, h=0..1, r=0..15), row = (r&3)+8*(r>>2)+4h
__global__ void mask_perm_k(const int* __restrict__ m, bf16_t* __restrict__ out) {
  int e = blockIdx.x * 256 + threadIdx.x;  // 64*2048*2 = 262144
  int h = e & 1;
  int q = (e >> 1) & 2047;
  int t = e >> 12;
  const int* mrow = m + (size_t)q * 2048 + t * 32;
  bf16x8 o0, o1;
#pragma unroll
  for (int r = 0; r < 8; ++r) {
    int row = (r & 3) + 8 * (r >> 2) + 4 * h;
    o0[r] = (bf16_t)(mrow[row] ? 1.f : 0.f);
  }
#pragma unroll
  for (int r = 8; r < 16; ++r) {
    int row = (r & 3) + 8 * (r >> 2) + 4 * h;
    o1[r - 8] = (bf16_t)(mrow[row] ? 1.f : 0.f);
  }
  reinterpret_cast<bf16x8*>(out)[(size_t)e * 2] = o0;
  reinterpret_cast<bf16x8*>(out)[(size_t)e * 2 + 1] = o1;
}

// ---------------- GEMM: C[m,n] = sum_k A[m,k]*Bw[n,k] + bias[n] ----------------
#define GLD_LDS(g, l) \
  __builtin_amdgcn_global_load_lds((const __attribute__((address_space(1))) void*)(g), \
                                   (__attribute__((address_space(3))) void*)(l), 16, 0, 0)

template <int OM>
__global__ __launch_bounds__(256, 2) void gemm_bias(
    const bf16_t* __restrict__ A, const bf16_t* __restrict__ Bw,
    const float* __restrict__ bias, void* __restrict__ Cout) {
  constexpr int K = 1024, N = 1024;
  __shared__ bf16_t As[128 * 32];
  __shared__ bf16_t Bs[128 * 32];
  const int tid = threadIdx.x;
  const int lane = tid & 63;
  const int wave = tid >> 6;
  const int wm = (wave >> 1) * 64, wn = (wave & 1) * 64;
  const int l15 = lane & 15, lhi = lane >> 4;
  const int bm = blockIdx.x, bn = blockIdx.y;
  const int r0 = tid >> 2;
  const int kc = (tid & 3) * 8;
  const bf16_t* ga = A + (size_t)(bm * 128 + r0) * K + kc;
  const bf16_t* gb = Bw + (size_t)(bn * 128 + r0) * K + kc;
  char* ldsA = (char*)As + wave * 1024;
  char* ldsB = (char*)Bs + wave * 1024;
  f32x4 acc[4][4] = {};
  for (int k0 = 0; k0 < K; k0 += 32) {
    __syncthreads();
    GLD_LDS(ga + k0, ldsA);
    GLD_LDS(ga + 64 * K + k0, ldsA + 4096);
    GLD_LDS(gb + k0, ldsB);
    GLD_LDS(gb + 64 * K + k0, ldsB + 4096);
    __syncthreads();
    bf16x8 af[4], bfv[4];
#pragma unroll
    for (int i = 0; i < 4; ++i)
      af[i] = *reinterpret_cast<const bf16x8*>(&As[(wm + i * 16 + l15) * 32 + lhi * 8]);
#pragma unroll
    for (int j = 0; j < 4; ++j)
      bfv[j] = *reinterpret_cast<const bf16x8*>(&Bs[(wn + j * 16 + l15) * 32 + lhi * 8]);
#pragma unroll
    for (int i = 0; i < 4; ++i)
#pragma unroll
      for (int j = 0; j < 4; ++j)
        acc[i][j] = __builtin_amdgcn_mfma_f32_16x16x32_bf16(af[i], bfv[j], acc[i][j], 0, 0, 0);
  }
#pragma unroll
  for (int i = 0; i < 4; ++i) {
#pragma unroll
    for (int j = 0; j < 4; ++j) {
      int n = bn * 128 + wn + j * 16 + l15;
      float bv = bias[n];
#pragma unroll
      for (int r = 0; r < 4; ++r) {
        int m = bm * 128 + wm + i * 16 + lhi * 4 + r;
        float val = acc[i][j][r] + bv;
        if (OM == 0) {
          ((bf16_t*)Cout)[(size_t)m * N + n] = f2bf(val);
        } else if (OM == 1) {
          int b = m >> 11, s = m & 2047;
          ((bf16_t*)Cout)[((size_t)b * 1024 + n) * 2048 + s] = f2bf(val);
        } else {
          ((float*)Cout)[(size_t)m * N + n] = val;
        }
      }
    }
  }
}

// ---------------- flash attention, 32x32 swapped-operand, barrier-free ----------------
// Qp,Kp: [B*S,1024] bf16. Vt: [B][1024][2048] bf16. maskP: permuted 0/1 table.
// Each wave: 32 q-rows, iterates 64 KV tiles of 32 keys. No LDS, no barriers.
__global__ __launch_bounds__(256, 3) void attn_kernel(
    const bf16_t* __restrict__ Qp, const bf16_t* __restrict__ Kp,
    const bf16_t* __restrict__ Vt, const bf16_t* __restrict__ maskP,
    bf16_t* __restrict__ Xb) {
  constexpr int S = 2048, D = 1024;
  constexpr float CS = 0.18033688011112042f;  // 0.125 * log2(e)
  const int tid = threadIdx.x;
  const int wave = tid >> 6, lane = tid & 63;
  const int l31 = lane & 31, h = lane >> 5;
  const int blk = blockIdx.x;           // 1024 blocks
  const int bh = blk >> 4, qt4 = blk & 15;
  const int b = bh >> 4, hd = bh & 15;
  const int q0 = qt4 * 128 + wave * 32;

  // Q as B-fragment: col q = l31, rows d = 16c + 8h + j
  const bf16_t* qbase = Qp + (size_t)(b * S + q0 + l31) * D + hd * 64 + h * 8;
  bf16x8 qf[4];
#pragma unroll
  for (int c = 0; c < 4; ++c)
    qf[c] = *reinterpret_cast<const bf16x8*>(qbase + 16 * c);

  const bf16_t* kbase = Kp + (size_t)b * S * D + hd * 64 + h * 8;
  const bf16_t* vbase = Vt + ((size_t)b * 1024 + hd * 64 + l31) * (size_t)S + h * 8;
  const bf16_t* mbase = maskP + ((size_t)(q0 + l31) * 2 + h) * 16;

  f32x16 o0 = {}, o1 = {};
  float mrun = -3.0e38f, lsum = 0.f;

  for (int k0 = 0; k0 < S; k0 += 32) {
    // S^T = K · Q^T : col = q = l31, row = k_local = (r&3)+8*(r>>2)+4h
    f32x16 s = {};
#pragma unroll
    for (int c = 0; c < 4; ++c) {
      bf16x8 kf = *reinterpret_cast<const bf16x8*>(kbase + (size_t)(k0 + l31) * D + 16 * c);
      s = __builtin_amdgcn_mfma_f32_32x32x16_bf16(kf, qf[c], s, 0, 0, 0);
    }
    bf16x8 mk0 = *reinterpret_cast<const bf16x8*>(mbase + ((size_t)(k0 >> 5) << 16));
    bf16x8 mk1 = *reinterpret_cast<const bf16x8*>(mbase + ((size_t)(k0 >> 5) << 16) + 8);
    // row max (unmasked max is valid: >= true masked max)
    float mt = s[0];
#pragma unroll
    for (int r = 1; r < 16; ++r) mt = fmaxf(mt, s[r]);
    mt = fmaxf(mt, __shfl_xor(mt, 32));
    if (!__all(mt - mrun <= 44.36142f)) {  // defer-max, THR = 8 / CS
      float mnew = fmaxf(mrun, mt);
      float alpha = __builtin_amdgcn_exp2f((mrun - mnew) * CS);
#pragma unroll
      for (int r = 0; r < 16; ++r) { o0[r] *= alpha; o1[r] *= alpha; }
      lsum *= alpha;
      mrun = mnew;
    }
    const float mc = mrun * CS;
    float p[16];
    float ts = 0.f;
#pragma unroll
    for (int r = 0; r < 16; ++r) {
      float pv = __builtin_amdgcn_exp2f(__builtin_fmaf(s[r], CS, -mc));
      pv *= (r < 8) ? bf2f(mk0[r]) : bf2f(mk1[r - 8]);
      p[r] = pv;
      ts += pv;
    }
    ts += __shfl_xor(ts, 32);
    lsum += ts;
    // pack p -> bf16 dwords; dw[i] = k rows (pair) per C-layout
    uint dw[8];
#pragma unroll
    for (int i = 0; i < 8; ++i) dw[i] = pack2(p[2 * i], p[2 * i + 1]);
    // rearrange into A-fragment (row q = l31, k = 8h + j per 16-chunk): xor-32 exchange
    uint e0 = (uint)__shfl_xor((int)(h ? dw[0] : dw[2]), 32);
    uint e1 = (uint)__shfl_xor((int)(h ? dw[1] : dw[3]), 32);
    uint e2 = (uint)__shfl_xor((int)(h ? dw[4] : dw[6]), 32);
    uint e3 = (uint)__shfl_xor((int)(h ? dw[5] : dw[7]), 32);
    uint4v ua0 = {h ? e0 : dw[0], h ? e1 : dw[1], h ? dw[2] : e0, h ? dw[3] : e1};
    uint4v ua1 = {h ? e2 : dw[4], h ? e3 : dw[5], h ? dw[6] : e2, h ? dw[7] : e3};
    bf16x8 pa0 = __builtin_bit_cast(bf16x8, ua0);
    bf16x8 pa1 = __builtin_bit_cast(bf16x8, ua1);
    // PV: O[q][d] += P·V, V as B-fragment from pre-transposed Vt
    {
      bf16x8 v00 = *reinterpret_cast<const bf16x8*>(vbase + k0);
      bf16x8 v01 = *reinterpret_cast<const bf16x8*>(vbase + k0 + 16);
      bf16x8 v10 = *reinterpret_cast<const bf16x8*>(vbase + (size_t)32 * S + k0);
      bf16x8 v11 = *reinterpret_cast<const bf16x8*>(vbase + (size_t)32 * S + k0 + 16);
      o0 = __builtin_amdgcn_mfma_f32_32x32x16_bf16(pa0, v00, o0, 0, 0, 0);
      o0 = __builtin_amdgcn_mfma_f32_32x32x16_bf16(pa1, v01, o0, 0, 0, 0);
      o1 = __builtin_amdgcn_mfma_f32_32x32x16_bf16(pa0, v10, o1, 0, 0, 0);
      o1 = __builtin_amdgcn_mfma_f32_32x32x16_bf16(pa1, v11, o1, 0, 0, 0);
    }
  }
  // epilogue: O col = d = l31 (+32), row q = (r&3)+8*(r>>2)+4h; fetch 1/l per row
  float linv = 1.f / lsum;
  bf16_t* xrow = Xb + (size_t)(b * S + q0) * D + hd * 64 + l31;
#pragma unroll
  for (int r = 0; r < 16; ++r) {
    int qrow = (r & 3) + 8 * (r >> 2) + 4 * h;
    float lr = __shfl(linv, qrow);
    xrow[(size_t)qrow * D] = f2bf(o0[r] * lr);
    xrow[(size_t)qrow * D + 32] = f2bf(o1[r] * lr);
  }
}

// ---------------- launch ----------------
extern "C" void kernel_launch(void* const* d_in, const int* in_sizes, int n_in,
                              void* d_out, int out_size, void* d_ws, size_t ws_size,
                              hipStream_t stream) {
  const float* q = (const float*)d_in[0];
  const float* k = (const float*)d_in[1];
  const float* v = (const float*)d_in[2];
  const int* mask = (const int*)d_in[3];
  const float* w_q = (const float*)d_in[4];
  const float* b_q = (const float*)d_in[5];
  const float* w_k = (const float*)d_in[6];
  const float* b_k = (const float*)d_in[7];
  const float* w_v = (const float*)d_in[8];
  const float* b_v = (const float*)d_in[9];
  const float* w_o = (const float*)d_in[10];
  const float* b_o = (const float*)d_in[11];

  char* ws = (char*)d_ws;
  const size_t SZ = (size_t)8192 * 1024 * 2;
  bf16_t* qc = (bf16_t*)(ws + 0 * SZ);
  bf16_t* kc = (bf16_t*)(ws + 1 * SZ);
  bf16_t* vc = (bf16_t*)(ws + 2 * SZ);
  bf16_t* Qp = (bf16_t*)(ws + 3 * SZ);
  bf16_t* Kp = (bf16_t*)(ws + 4 * SZ);
  bf16_t* Vt = (bf16_t*)(ws + 5 * SZ);
  bf16_t* Xb = (bf16_t*)(ws + 6 * SZ);
  bf16_t* maskP = (bf16_t*)(ws + 7 * SZ);  // 8 MiB permuted 0/1 table
  bf16_t* wqb = (bf16_t*)(ws + 7 * SZ + 8388608);
  bf16_t* wkb = wqb + 1048576;
  bf16_t* wvb = wkb + 1048576;
  bf16_t* wob = wvb + 1048576;

  cvt_f2b<<<8192, 256, 0, stream>>>(q, qc, 2097152);
  cvt_f2b<<<8192, 256, 0, stream>>>(k, kc, 2097152);
  cvt_f2b<<<8192, 256, 0, stream>>>(v, vc, 2097152);
  cvt_f2b<<<1024, 256, 0, stream>>>(w_q, wqb, 262144);
  cvt_f2b<<<1024, 256, 0, stream>>>(w_k, wkb, 262144);
  cvt_f2b<<<1024, 256, 0, stream>>>(w_v, wvb, 262144);
  cvt_f2b<<<1024, 256, 0, stream>>>(w_o, wob, 262144);
  mask_perm_k<<<1024, 256, 0, stream>>>(mask, maskP);

  dim3 gg(64, 8);
  gemm_bias<0><<<gg, 256, 0, stream>>>(qc, wqb, b_q, Qp);
  gemm_bias<0><<<gg, 256, 0, stream>>>(kc, wkb, b_k, Kp);
  gemm_bias<1><<<gg, 256, 0, stream>>>(vc, wvb, b_v, Vt);
  attn_kernel<<<1024, 256, 0, stream>>>(Qp, Kp, Vt, maskP, Xb);
  gemm_bias<2><<<gg, 256, 0, stream>>>(Xb, wob, b_o, d_out);
}

// Round 3
// 389.423 us; speedup vs baseline: 1.6514x; 1.0779x over previous
//
#include <hip/hip_runtime.h>

typedef __bf16 bf16_t;
typedef __bf16 bf16x4 __attribute__((ext_vector_type(4)));
typedef __bf16 bf16x8 __attribute__((ext_vector_type(8)));
typedef float f32x4 __attribute__((ext_vector_type(4)));
typedef float f32x16 __attribute__((ext_vector_type(16)));
typedef unsigned int uint;
typedef uint uint4v __attribute__((ext_vector_type(4)));

static __device__ __forceinline__ bf16_t f2bf(float f) {
  unsigned u = __builtin_bit_cast(unsigned, f);
  u = (u + 0x7fff + ((u >> 16) & 1)) >> 16;
  unsigned short h = (unsigned short)u;
  return __builtin_bit_cast(bf16_t, h);
}
static __device__ __forceinline__ uint pack2(float a, float b) {
  uint lo = __builtin_bit_cast(unsigned short, (bf16_t)a);
  uint hi = __builtin_bit_cast(unsigned short, (bf16_t)b);
  return lo | (hi << 16);
}

// ---------------- conversion kernels ----------------
__global__ void cvt_f2b(const float* __restrict__ in, bf16_t* __restrict__ out, int n4) {
  int i = blockIdx.x * blockDim.x + threadIdx.x;
  if (i >= n4) return;
  const float4 f = reinterpret_cast<const float4*>(in)[i];
  bf16x4 o;
  o[0] = f2bf(f.x); o[1] = f2bf(f.y); o[2] = f2bf(f.z); o[3] = f2bf(f.w);
  reinterpret_cast<bf16x4*>(out)[i] = o;
}

// mask -> packed bits, [t][q] uint32. bit j   = mask[q][32t + (j&3)+8*(j>>2)]
//                                    bit 16+j = mask[q][32t + (j&3)+8*(j>>2)+4]
__global__ void mask_bits_k(const int* __restrict__ m, uint* __restrict__ out) {
  int i = blockIdx.x * 256 + threadIdx.x;  // 131072
  int q = i & 2047, t = i >> 11;
  const int* mrow = m + (size_t)q * 2048 + t * 32;
  uint bits = 0;
#pragma unroll
  for (int j = 0; j < 16; ++j) {
    int r0 = (j & 3) + 8 * (j >> 2);
    bits |= (mrow[r0] ? 1u : 0u) << j;
    bits |= (mrow[r0 + 4] ? 1u : 0u) << (16 + j);
  }
  out[(size_t)t * 2048 + q] = bits;
}

// ---------------- GEMM: C[m,n] = sum_k A[m,k]*Bw[n,k] + bias[n] ----------------
#define GLD_LDS(g, l) \
  __builtin_amdgcn_global_load_lds((const __attribute__((address_space(1))) void*)(g), \
                                   (__attribute__((address_space(3))) void*)(l), 16, 0, 0)

template <int OM>
__global__ __launch_bounds__(256, 2) void gemm_bias(
    const bf16_t* __restrict__ A, const bf16_t* __restrict__ Bw,
    const float* __restrict__ bias, void* __restrict__ Cout) {
  constexpr int K = 1024, N = 1024;
  __shared__ bf16_t As[128 * 32];
  __shared__ bf16_t Bs[128 * 32];
  const int tid = threadIdx.x;
  const int lane = tid & 63;
  const int wave = tid >> 6;
  const int wm = (wave >> 1) * 64, wn = (wave & 1) * 64;
  const int l15 = lane & 15, lhi = lane >> 4;
  const int bm = blockIdx.x, bn = blockIdx.y;
  const int r0 = tid >> 2;
  const int kc = (tid & 3) * 8;
  const bf16_t* ga = A + (size_t)(bm * 128 + r0) * K + kc;
  const bf16_t* gb = Bw + (size_t)(bn * 128 + r0) * K + kc;
  char* ldsA = (char*)As + wave * 1024;
  char* ldsB = (char*)Bs + wave * 1024;
  f32x4 acc[4][4] = {};
  for (int k0 = 0; k0 < K; k0 += 32) {
    __syncthreads();
    GLD_LDS(ga + k0, ldsA);
    GLD_LDS(ga + 64 * K + k0, ldsA + 4096);
    GLD_LDS(gb + k0, ldsB);
    GLD_LDS(gb + 64 * K + k0, ldsB + 4096);
    __syncthreads();
    bf16x8 af[4], bfv[4];
#pragma unroll
    for (int i = 0; i < 4; ++i)
      af[i] = *reinterpret_cast<const bf16x8*>(&As[(wm + i * 16 + l15) * 32 + lhi * 8]);
#pragma unroll
    for (int j = 0; j < 4; ++j)
      bfv[j] = *reinterpret_cast<const bf16x8*>(&Bs[(wn + j * 16 + l15) * 32 + lhi * 8]);
#pragma unroll
    for (int i = 0; i < 4; ++i)
#pragma unroll
      for (int j = 0; j < 4; ++j)
        acc[i][j] = __builtin_amdgcn_mfma_f32_16x16x32_bf16(af[i], bfv[j], acc[i][j], 0, 0, 0);
  }
#pragma unroll
  for (int i = 0; i < 4; ++i) {
#pragma unroll
    for (int j = 0; j < 4; ++j) {
      int n = bn * 128 + wn + j * 16 + l15;
      float bv = bias[n];
#pragma unroll
      for (int r = 0; r < 4; ++r) {
        int m = bm * 128 + wm + i * 16 + lhi * 4 + r;
        float val = acc[i][j][r] + bv;
        if (OM == 0) {
          ((bf16_t*)Cout)[(size_t)m * N + n] = f2bf(val);
        } else if (OM == 1) {
          int b = m >> 11, s = m & 2047;
          ((bf16_t*)Cout)[((size_t)b * 1024 + n) * 2048 + s] = f2bf(val);
        } else {
          ((float*)Cout)[(size_t)m * N + n] = val;
        }
      }
    }
  }
}

// ---------------- flash attention, 32x32 swapped-operand, reg-prefetch pipeline ----------------
__global__ __launch_bounds__(256, 2) void attn_kernel(
    const bf16_t* __restrict__ Qp, const bf16_t* __restrict__ Kp,
    const bf16_t* __restrict__ Vt, const uint* __restrict__ maskbits,
    bf16_t* __restrict__ Xb) {
  constexpr int S = 2048, D = 1024;
  constexpr float CS = 0.18033688011112042f;  // 0.125 * log2(e)
  const int tid = threadIdx.x;
  const int wave = tid >> 6, lane = tid & 63;
  const int l31 = lane & 31, h = lane >> 5;
  const int blk = blockIdx.x;  // 1024 blocks
  const int bh = blk >> 4, qt4 = blk & 15;
  const int b = bh >> 4, hd = bh & 15;
  const int q0 = qt4 * 128 + wave * 32;

  // Q as B-fragment: col q = l31, rows d = 16c + 8h + j
  const bf16_t* qbase = Qp + (size_t)(b * S + q0 + l31) * D + hd * 64 + h * 8;
  bf16x8 qf[4];
#pragma unroll
  for (int c = 0; c < 4; ++c)
    qf[c] = *reinterpret_cast<const bf16x8*>(qbase + 16 * c);

  const bf16_t* kbase = Kp + (size_t)b * S * D + hd * 64 + h * 8;
  const bf16_t* vbase = Vt + ((size_t)b * 1024 + hd * 64 + l31) * (size_t)S + h * 8;
  const uint* mbase = maskbits + q0 + l31;

  f32x16 o0 = {}, o1 = {};
  float mrun = -3.0e38f, lsum = 0.f;

  // prologue: load tile 0 into current regs
  bf16x8 kc[4], vc[4];
  uint mbc;
  {
    const bf16_t* krow = kbase + (size_t)l31 * D;
#pragma unroll
    for (int c = 0; c < 4; ++c) kc[c] = *reinterpret_cast<const bf16x8*>(krow + 16 * c);
    vc[0] = *reinterpret_cast<const bf16x8*>(vbase);
    vc[1] = *reinterpret_cast<const bf16x8*>(vbase + 16);
    vc[2] = *reinterpret_cast<const bf16x8*>(vbase + (size_t)32 * S);
    vc[3] = *reinterpret_cast<const bf16x8*>(vbase + (size_t)32 * S + 16);
    mbc = mbase[0];
  }

#pragma unroll 2
  for (int t = 0; t < 64; ++t) {
    const int tn = (t + 1) & 63;  // wraps to 0 on last iter (harmless reload)
    // ---- issue next-tile loads (prefetch) ----
    bf16x8 kn[4], vn[4];
    uint mbn;
    {
      const bf16_t* krow = kbase + (size_t)(tn * 32 + l31) * D;
#pragma unroll
      for (int c = 0; c < 4; ++c) kn[c] = *reinterpret_cast<const bf16x8*>(krow + 16 * c);
      const bf16_t* vrow = vbase + tn * 32;
      vn[0] = *reinterpret_cast<const bf16x8*>(vrow);
      vn[1] = *reinterpret_cast<const bf16x8*>(vrow + 16);
      vn[2] = *reinterpret_cast<const bf16x8*>(vrow + (size_t)32 * S);
      vn[3] = *reinterpret_cast<const bf16x8*>(vrow + (size_t)32 * S + 16);
      mbn = mbase[tn * 2048];
    }
    // ---- QK^T on current tile ----
    f32x16 s = {};
    __builtin_amdgcn_s_setprio(1);
#pragma unroll
    for (int c = 0; c < 4; ++c)
      s = __builtin_amdgcn_mfma_f32_32x32x16_bf16(kc[c], qf[c], s, 0, 0, 0);
    __builtin_amdgcn_s_setprio(0);
    // ---- softmax (in-register; row = one q per lane-pair) ----
    const uint mbh = mbc >> (h << 4);  // low/high 16 bits per h
    // tree max over 16 regs + cross-half
    float x0 = fmaxf(s[0], s[1]), x1 = fmaxf(s[2], s[3]);
    float x2 = fmaxf(s[4], s[5]), x3 = fmaxf(s[6], s[7]);
    float x4 = fmaxf(s[8], s[9]), x5 = fmaxf(s[10], s[11]);
    float x6 = fmaxf(s[12], s[13]), x7 = fmaxf(s[14], s[15]);
    x0 = fmaxf(x0, x1); x2 = fmaxf(x2, x3); x4 = fmaxf(x4, x5); x6 = fmaxf(x6, x7);
    x0 = fmaxf(x0, x2); x4 = fmaxf(x4, x6);
    float mt = fmaxf(x0, x4);
    mt = fmaxf(mt, __shfl_xor(mt, 32));
    if (!__all(mt - mrun <= 44.36142f)) {  // defer-max, THR = 8 / CS
      float mnew = fmaxf(mrun, mt);
      float alpha = __builtin_amdgcn_exp2f((mrun - mnew) * CS);
#pragma unroll
      for (int r = 0; r < 16; ++r) { o0[r] *= alpha; o1[r] *= alpha; }
      lsum *= alpha;
      mrun = mnew;
    }
    const float mc = mrun * CS;
    float p[16];
#pragma unroll
    for (int r = 0; r < 16; ++r) {
      float pv = __builtin_amdgcn_exp2f(__builtin_fmaf(s[r], CS, -mc));
      uint smask = (uint)(((int)(mbh << (31 - r))) >> 31);  // all-ones if unmasked
      p[r] = __builtin_bit_cast(float, __builtin_bit_cast(uint, pv) & smask);
    }
    // tree sum
    float t0 = p[0] + p[1], t1 = p[2] + p[3], t2 = p[4] + p[5], t3 = p[6] + p[7];
    float t4 = p[8] + p[9], t5 = p[10] + p[11], t6 = p[12] + p[13], t7 = p[14] + p[15];
    t0 += t1; t2 += t3; t4 += t5; t6 += t7;
    t0 += t2; t4 += t6;
    float ts = t0 + t4;
    ts += __shfl_xor(ts, 32);
    lsum += ts;
    // pack p -> bf16 dwords, rearrange into A-fragment via xor-32 exchange
    uint dw[8];
#pragma unroll
    for (int i = 0; i < 8; ++i) dw[i] = pack2(p[2 * i], p[2 * i + 1]);
    uint e0 = (uint)__shfl_xor((int)(h ? dw[0] : dw[2]), 32);
    uint e1 = (uint)__shfl_xor((int)(h ? dw[1] : dw[3]), 32);
    uint e2 = (uint)__shfl_xor((int)(h ? dw[4] : dw[6]), 32);
    uint e3 = (uint)__shfl_xor((int)(h ? dw[5] : dw[7]), 32);
    uint4v ua0 = {h ? e0 : dw[0], h ? e1 : dw[1], h ? dw[2] : e0, h ? dw[3] : e1};
    uint4v ua1 = {h ? e2 : dw[4], h ? e3 : dw[5], h ? dw[6] : e2, h ? dw[7] : e3};
    bf16x8 pa0 = __builtin_bit_cast(bf16x8, ua0);
    bf16x8 pa1 = __builtin_bit_cast(bf16x8, ua1);
    // ---- PV on current tile ----
    __builtin_amdgcn_s_setprio(1);
    o0 = __builtin_amdgcn_mfma_f32_32x32x16_bf16(pa0, vc[0], o0, 0, 0, 0);
    o0 = __builtin_amdgcn_mfma_f32_32x32x16_bf16(pa1, vc[1], o0, 0, 0, 0);
    o1 = __builtin_amdgcn_mfma_f32_32x32x16_bf16(pa0, vc[2], o1, 0, 0, 0);
    o1 = __builtin_amdgcn_mfma_f32_32x32x16_bf16(pa1, vc[3], o1, 0, 0, 0);
    __builtin_amdgcn_s_setprio(0);
    // ---- rotate buffers ----
#pragma unroll
    for (int c = 0; c < 4; ++c) { kc[c] = kn[c]; vc[c] = vn[c]; }
    mbc = mbn;
  }
  // epilogue
  float linv = 1.f / lsum;
  bf16_t* xrow = Xb + (size_t)(b * S + q0) * D + hd * 64 + l31;
#pragma unroll
  for (int r = 0; r < 16; ++r) {
    int qrow = (r & 3) + 8 * (r >> 2) + 4 * h;
    float lr = __shfl(linv, qrow);
    xrow[(size_t)qrow * D] = f2bf(o0[r] * lr);
    xrow[(size_t)qrow * D + 32] = f2bf(o1[r] * lr);
  }
}

// ---------------- launch ----------------
extern "C" void kernel_launch(void* const* d_in, const int* in_sizes, int n_in,
                              void* d_out, int out_size, void* d_ws, size_t ws_size,
                              hipStream_t stream) {
  const float* q = (const float*)d_in[0];
  const float* k = (const float*)d_in[1];
  const float* v = (const float*)d_in[2];
  const int* mask = (const int*)d_in[3];
  const float* w_q = (const float*)d_in[4];
  const float* b_q = (const float*)d_in[5];
  const float* w_k = (const float*)d_in[6];
  const float* b_k = (const float*)d_in[7];
  const float* w_v = (const float*)d_in[8];
  const float* b_v = (const float*)d_in[9];
  const float* w_o = (const float*)d_in[10];
  const float* b_o = (const float*)d_in[11];

  char* ws = (char*)d_ws;
  const size_t SZ = (size_t)8192 * 1024 * 2;
  bf16_t* qc = (bf16_t*)(ws + 0 * SZ);
  bf16_t* kc = (bf16_t*)(ws + 1 * SZ);
  bf16_t* vc = (bf16_t*)(ws + 2 * SZ);
  bf16_t* Qp = (bf16_t*)(ws + 3 * SZ);
  bf16_t* Kp = (bf16_t*)(ws + 4 * SZ);
  bf16_t* Vt = (bf16_t*)(ws + 5 * SZ);
  bf16_t* Xb = (bf16_t*)(ws + 6 * SZ);
  uint* maskB = (uint*)(ws + 7 * SZ);  // 512 KiB packed mask bits
  bf16_t* wqb = (bf16_t*)(ws + 7 * SZ + 8388608);
  bf16_t* wkb = wqb + 1048576;
  bf16_t* wvb = wkb + 1048576;
  bf16_t* wob = wvb + 1048576;

  cvt_f2b<<<8192, 256, 0, stream>>>(q, qc, 2097152);
  cvt_f2b<<<8192, 256, 0, stream>>>(k, kc, 2097152);
  cvt_f2b<<<8192, 256, 0, stream>>>(v, vc, 2097152);
  cvt_f2b<<<1024, 256, 0, stream>>>(w_q, wqb, 262144);
  cvt_f2b<<<1024, 256, 0, stream>>>(w_k, wkb, 262144);
  cvt_f2b<<<1024, 256, 0, stream>>>(w_v, wvb, 262144);
  cvt_f2b<<<1024, 256, 0, stream>>>(w_o, wob, 262144);
  mask_bits_k<<<512, 256, 0, stream>>>(mask, maskB);

  dim3 gg(64, 8);
  gemm_bias<0><<<gg, 256, 0, stream>>>(qc, wqb, b_q, Qp);
  gemm_bias<0><<<gg, 256, 0, stream>>>(kc, wkb, b_k, Kp);
  gemm_bias<1><<<gg, 256, 0, stream>>>(vc, wvb, b_v, Vt);
  attn_kernel<<<1024, 256, 0, stream>>>(Qp, Kp, Vt, maskB, Xb);
  gemm_bias<2><<<gg, 256, 0, stream>>>(Xb, wob, b_o, d_out);
}

// Round 4
// 268.720 us; speedup vs baseline: 2.3932x; 1.4492x over previous
//
#include <hip/hip_runtime.h>

typedef __bf16 bf16_t;
typedef __bf16 bf16x4 __attribute__((ext_vector_type(4)));
typedef __bf16 bf16x8 __attribute__((ext_vector_type(8)));
typedef float f32x4 __attribute__((ext_vector_type(4)));
typedef float f32x16 __attribute__((ext_vector_type(16)));
typedef unsigned int uint;
typedef uint uint4v __attribute__((ext_vector_type(4)));

static __device__ __forceinline__ bf16_t f2bf(float f) {
  unsigned u = __builtin_bit_cast(unsigned, f);
  u = (u + 0x7fff + ((u >> 16) & 1)) >> 16;
  unsigned short h = (unsigned short)u;
  return __builtin_bit_cast(bf16_t, h);
}
static __device__ __forceinline__ uint pack2(float a, float b) {
  uint lo = __builtin_bit_cast(unsigned short, (bf16_t)a);
  uint hi = __builtin_bit_cast(unsigned short, (bf16_t)b);
  return lo | (hi << 16);
}

// ---------------- conversion kernels ----------------
__global__ void cvt_f2b(const float* __restrict__ in, bf16_t* __restrict__ out, int n4) {
  int i = blockIdx.x * blockDim.x + threadIdx.x;
  if (i >= n4) return;
  const float4 f = reinterpret_cast<const float4*>(in)[i];
  bf16x4 o;
  o[0] = f2bf(f.x); o[1] = f2bf(f.y); o[2] = f2bf(f.z); o[3] = f2bf(f.w);
  reinterpret_cast<bf16x4*>(out)[i] = o;
}

// mask -> packed bits, [t][q] uint32. bit j   = mask[q][32t + (j&3)+8*(j>>2)]
//                                    bit 16+j = mask[q][32t + (j&3)+8*(j>>2)+4]
__global__ void mask_bits_k(const int* __restrict__ m, uint* __restrict__ out) {
  int i = blockIdx.x * 256 + threadIdx.x;  // 131072
  int q = i & 2047, t = i >> 11;
  const int* mrow = m + (size_t)q * 2048 + t * 32;
  uint bits = 0;
#pragma unroll
  for (int j = 0; j < 16; ++j) {
    int r0 = (j & 3) + 8 * (j >> 2);
    bits |= (mrow[r0] ? 1u : 0u) << j;
    bits |= (mrow[r0 + 4] ? 1u : 0u) << (16 + j);
  }
  out[(size_t)t * 2048 + q] = bits;
}

// ---------------- GEMM: C[m,n] = sum_k A[m,k]*Bw[n,k] + bias[n] ----------------
#define GLD_LDS(g, l) \
  __builtin_amdgcn_global_load_lds((const __attribute__((address_space(1))) void*)(g), \
                                   (__attribute__((address_space(3))) void*)(l), 16, 0, 0)

template <int OM>
__global__ __launch_bounds__(256, 2) void gemm_bias(
    const bf16_t* __restrict__ A, const bf16_t* __restrict__ Bw,
    const float* __restrict__ bias, void* __restrict__ Cout) {
  constexpr int K = 1024, N = 1024;
  __shared__ bf16_t As[128 * 32];
  __shared__ bf16_t Bs[128 * 32];
  const int tid = threadIdx.x;
  const int lane = tid & 63;
  const int wave = tid >> 6;
  const int wm = (wave >> 1) * 64, wn = (wave & 1) * 64;
  const int l15 = lane & 15, lhi = lane >> 4;
  const int bm = blockIdx.x, bn = blockIdx.y;
  const int r0 = tid >> 2;
  const int kc = (tid & 3) * 8;
  const bf16_t* ga = A + (size_t)(bm * 128 + r0) * K + kc;
  const bf16_t* gb = Bw + (size_t)(bn * 128 + r0) * K + kc;
  char* ldsA = (char*)As + wave * 1024;
  char* ldsB = (char*)Bs + wave * 1024;
  f32x4 acc[4][4] = {};
  for (int k0 = 0; k0 < K; k0 += 32) {
    __syncthreads();
    GLD_LDS(ga + k0, ldsA);
    GLD_LDS(ga + 64 * K + k0, ldsA + 4096);
    GLD_LDS(gb + k0, ldsB);
    GLD_LDS(gb + 64 * K + k0, ldsB + 4096);
    __syncthreads();
    bf16x8 af[4], bfv[4];
#pragma unroll
    for (int i = 0; i < 4; ++i)
      af[i] = *reinterpret_cast<const bf16x8*>(&As[(wm + i * 16 + l15) * 32 + lhi * 8]);
#pragma unroll
    for (int j = 0; j < 4; ++j)
      bfv[j] = *reinterpret_cast<const bf16x8*>(&Bs[(wn + j * 16 + l15) * 32 + lhi * 8]);
#pragma unroll
    for (int i = 0; i < 4; ++i)
#pragma unroll
      for (int j = 0; j < 4; ++j)
        acc[i][j] = __builtin_amdgcn_mfma_f32_16x16x32_bf16(af[i], bfv[j], acc[i][j], 0, 0, 0);
  }
#pragma unroll
  for (int i = 0; i < 4; ++i) {
#pragma unroll
    for (int j = 0; j < 4; ++j) {
      int n = bn * 128 + wn + j * 16 + l15;
      float bv = bias[n];
#pragma unroll
      for (int r = 0; r < 4; ++r) {
        int m = bm * 128 + wm + i * 16 + lhi * 4 + r;
        float val = acc[i][j][r] + bv;
        if (OM == 0) {
          ((bf16_t*)Cout)[(size_t)m * N + n] = f2bf(val);
        } else if (OM == 1) {
          int b = m >> 11, s = m & 2047;
          ((bf16_t*)Cout)[((size_t)b * 1024 + n) * 2048 + s] = f2bf(val);
        } else {
          ((float*)Cout)[(size_t)m * N + n] = val;
        }
      }
    }
  }
}

// ---------------- flash attention: LDS-staged tiles, 32x32 swapped-operand ----------------
// Grid 1024: blk = qt4*64 + bh  (all 16 q-tiles of one (b,h) land on one XCD).
__global__ __launch_bounds__(256, 4) void attn_kernel(
    const bf16_t* __restrict__ Qp, const bf16_t* __restrict__ Kp,
    const bf16_t* __restrict__ Vt, const uint* __restrict__ maskbits,
    bf16_t* __restrict__ Xb) {
  constexpr int S = 2048, D = 1024;
  constexpr float CS = 0.18033688011112042f;  // 0.125 * log2(e)
  __shared__ __align__(16) bf16_t Ks[2][32][72];  // 64 cols + 8 pad
  __shared__ __align__(16) bf16_t Vs[2][64][40];  // 32 cols + 8 pad
  const int tid = threadIdx.x;
  const int wave = tid >> 6, lane = tid & 63;
  const int l31 = lane & 31, h = lane >> 5;
  const int blk = blockIdx.x;
  const int bh = blk & 63, qt4 = blk >> 6;
  const int b = bh >> 4, hd = bh & 15;
  const int q0 = qt4 * 128 + wave * 32;

  // staging decomposition (256 threads)
  const int rK = tid >> 3, sK = tid & 7;  // K: 32 rows x 8 slots of 16B
  const int rV = tid >> 2, sV = tid & 3;  // V: 64 rows x 4 slots of 16B
  const bf16_t* gK = Kp + (size_t)b * S * D + (size_t)rK * D + hd * 64 + sK * 8;
  const bf16_t* gV = Vt + ((size_t)b * 1024 + hd * 64 + rV) * (size_t)S + sV * 8;

  // Q as B-fragment: col q = l31, rows d = 16c + 8h + j
  const bf16_t* qbase = Qp + (size_t)(b * S + q0 + l31) * D + hd * 64 + h * 8;
  bf16x8 qf[4];
#pragma unroll
  for (int c = 0; c < 4; ++c)
    qf[c] = *reinterpret_cast<const bf16x8*>(qbase + 16 * c);

  const uint* mbase = maskbits + q0 + l31;

  f32x16 o0 = {}, o1 = {};
  float mrun = 0.f, lsum = 0.f;  // fixed ref point; rescale only if scores exceed THR

  // prologue: stage tile 0
  {
    bf16x8 k0r = *reinterpret_cast<const bf16x8*>(gK);
    bf16x8 v0r = *reinterpret_cast<const bf16x8*>(gV);
    *reinterpret_cast<bf16x8*>(&Ks[0][rK][sK * 8]) = k0r;
    *reinterpret_cast<bf16x8*>(&Vs[0][rV][sV * 8]) = v0r;
    __syncthreads();
  }

#pragma unroll 2
  for (int t = 0; t < 64; ++t) {
    const int cur = t & 1, nxt = cur ^ 1;
    const bool pf = (t < 63);
    // ---- issue next-tile global loads (hidden under compute) ----
    bf16x8 kreg, vreg;
    if (pf) {
      kreg = *reinterpret_cast<const bf16x8*>(gK + (size_t)(t + 1) * 32 * D);
      vreg = *reinterpret_cast<const bf16x8*>(gV + (t + 1) * 32);
    }
    uint mbc = mbase[t * 2048];
    // ---- QK^T from LDS ----
    f32x16 s = {};
    __builtin_amdgcn_s_setprio(1);
#pragma unroll
    for (int c = 0; c < 4; ++c) {
      bf16x8 kf = *reinterpret_cast<const bf16x8*>(&Ks[cur][l31][h * 8 + 16 * c]);
      s = __builtin_amdgcn_mfma_f32_32x32x16_bf16(kf, qf[c], s, 0, 0, 0);
    }
    __builtin_amdgcn_s_setprio(0);
    // ---- softmax ----
    const uint mbh = mbc >> (h << 4);
    float x0 = fmaxf(s[0], s[1]), x1 = fmaxf(s[2], s[3]);
    float x2 = fmaxf(s[4], s[5]), x3 = fmaxf(s[6], s[7]);
    float x4 = fmaxf(s[8], s[9]), x5 = fmaxf(s[10], s[11]);
    float x6 = fmaxf(s[12], s[13]), x7 = fmaxf(s[14], s[15]);
    x0 = fmaxf(x0, x1); x2 = fmaxf(x2, x3); x4 = fmaxf(x4, x5); x6 = fmaxf(x6, x7);
    x0 = fmaxf(x0, x2); x4 = fmaxf(x4, x6);
    float mt = fmaxf(x0, x4);
    mt = fmaxf(mt, __shfl_xor(mt, 32));
    if (!__all(mt - mrun <= 44.36142f)) {  // defer-max safety (never for |s|<~44)
      float mnew = fmaxf(mrun, mt);
      float alpha = __builtin_amdgcn_exp2f((mrun - mnew) * CS);
#pragma unroll
      for (int r = 0; r < 16; ++r) { o0[r] *= alpha; o1[r] *= alpha; }
      lsum *= alpha;
      mrun = mnew;
    }
    const float mc = mrun * CS;
    float p[16];
#pragma unroll
    for (int r = 0; r < 16; ++r) {
      float pv = __builtin_amdgcn_exp2f(__builtin_fmaf(s[r], CS, -mc));
      uint smask = (uint)(((int)(mbh << (31 - r))) >> 31);  // sign-extend bit r
      p[r] = __builtin_bit_cast(float, __builtin_bit_cast(uint, pv) & smask);
    }
    float t0 = p[0] + p[1], t1 = p[2] + p[3], t2 = p[4] + p[5], t3 = p[6] + p[7];
    float t4 = p[8] + p[9], t5 = p[10] + p[11], t6 = p[12] + p[13], t7 = p[14] + p[15];
    t0 += t1; t2 += t3; t4 += t5; t6 += t7;
    t0 += t2; t4 += t6;
    float ts = t0 + t4;
    ts += __shfl_xor(ts, 32);
    lsum += ts;
    // pack p -> bf16 dwords, rearrange into A-fragment via xor-32 exchange
    uint dw[8];
#pragma unroll
    for (int i = 0; i < 8; ++i) dw[i] = pack2(p[2 * i], p[2 * i + 1]);
    uint e0 = (uint)__shfl_xor((int)(h ? dw[0] : dw[2]), 32);
    uint e1 = (uint)__shfl_xor((int)(h ? dw[1] : dw[3]), 32);
    uint e2 = (uint)__shfl_xor((int)(h ? dw[4] : dw[6]), 32);
    uint e3 = (uint)__shfl_xor((int)(h ? dw[5] : dw[7]), 32);
    uint4v ua0 = {h ? e0 : dw[0], h ? e1 : dw[1], h ? dw[2] : e0, h ? dw[3] : e1};
    uint4v ua1 = {h ? e2 : dw[4], h ? e3 : dw[5], h ? dw[6] : e2, h ? dw[7] : e3};
    bf16x8 pa0 = __builtin_bit_cast(bf16x8, ua0);
    bf16x8 pa1 = __builtin_bit_cast(bf16x8, ua1);
    // ---- PV from LDS ----
    {
      bf16x8 v00 = *reinterpret_cast<const bf16x8*>(&Vs[cur][l31][h * 8]);
      bf16x8 v01 = *reinterpret_cast<const bf16x8*>(&Vs[cur][l31][16 + h * 8]);
      bf16x8 v10 = *reinterpret_cast<const bf16x8*>(&Vs[cur][32 + l31][h * 8]);
      bf16x8 v11 = *reinterpret_cast<const bf16x8*>(&Vs[cur][32 + l31][16 + h * 8]);
      __builtin_amdgcn_s_setprio(1);
      o0 = __builtin_amdgcn_mfma_f32_32x32x16_bf16(pa0, v00, o0, 0, 0, 0);
      o0 = __builtin_amdgcn_mfma_f32_32x32x16_bf16(pa1, v01, o0, 0, 0, 0);
      o1 = __builtin_amdgcn_mfma_f32_32x32x16_bf16(pa0, v10, o1, 0, 0, 0);
      o1 = __builtin_amdgcn_mfma_f32_32x32x16_bf16(pa1, v11, o1, 0, 0, 0);
      __builtin_amdgcn_s_setprio(0);
    }
    // ---- write staged tile t+1, one barrier per tile ----
    if (pf) {
      *reinterpret_cast<bf16x8*>(&Ks[nxt][rK][sK * 8]) = kreg;
      *reinterpret_cast<bf16x8*>(&Vs[nxt][rV][sV * 8]) = vreg;
      __syncthreads();
    }
  }
  // epilogue
  float linv = 1.f / lsum;
  bf16_t* xrow = Xb + (size_t)(b * S + q0) * D + hd * 64 + l31;
#pragma unroll
  for (int r = 0; r < 16; ++r) {
    int qrow = (r & 3) + 8 * (r >> 2) + 4 * h;
    float lr = __shfl(linv, qrow);
    xrow[(size_t)qrow * D] = f2bf(o0[r] * lr);
    xrow[(size_t)qrow * D + 32] = f2bf(o1[r] * lr);
  }
}

// ---------------- launch ----------------
extern "C" void kernel_launch(void* const* d_in, const int* in_sizes, int n_in,
                              void* d_out, int out_size, void* d_ws, size_t ws_size,
                              hipStream_t stream) {
  const float* q = (const float*)d_in[0];
  const float* k = (const float*)d_in[1];
  const float* v = (const float*)d_in[2];
  const int* mask = (const int*)d_in[3];
  const float* w_q = (const float*)d_in[4];
  const float* b_q = (const float*)d_in[5];
  const float* w_k = (const float*)d_in[6];
  const float* b_k = (const float*)d_in[7];
  const float* w_v = (const float*)d_in[8];
  const float* b_v = (const float*)d_in[9];
  const float* w_o = (const float*)d_in[10];
  const float* b_o = (const float*)d_in[11];

  char* ws = (char*)d_ws;
  const size_t SZ = (size_t)8192 * 1024 * 2;
  bf16_t* qc = (bf16_t*)(ws + 0 * SZ);
  bf16_t* kc = (bf16_t*)(ws + 1 * SZ);
  bf16_t* vc = (bf16_t*)(ws + 2 * SZ);
  bf16_t* Qp = (bf16_t*)(ws + 3 * SZ);
  bf16_t* Kp = (bf16_t*)(ws + 4 * SZ);
  bf16_t* Vt = (bf16_t*)(ws + 5 * SZ);
  bf16_t* Xb = (bf16_t*)(ws + 6 * SZ);
  uint* maskB = (uint*)(ws + 7 * SZ);  // 512 KiB packed mask bits
  bf16_t* wqb = (bf16_t*)(ws + 7 * SZ + 8388608);
  bf16_t* wkb = wqb + 1048576;
  bf16_t* wvb = wkb + 1048576;
  bf16_t* wob = wvb + 1048576;

  cvt_f2b<<<8192, 256, 0, stream>>>(q, qc, 2097152);
  cvt_f2b<<<8192, 256, 0, stream>>>(k, kc, 2097152);
  cvt_f2b<<<8192, 256, 0, stream>>>(v, vc, 2097152);
  cvt_f2b<<<1024, 256, 0, stream>>>(w_q, wqb, 262144);
  cvt_f2b<<<1024, 256, 0, stream>>>(w_k, wkb, 262144);
  cvt_f2b<<<1024, 256, 0, stream>>>(w_v, wvb, 262144);
  cvt_f2b<<<1024, 256, 0, stream>>>(w_o, wob, 262144);
  mask_bits_k<<<512, 256, 0, stream>>>(mask, maskB);

  dim3 gg(64, 8);
  gemm_bias<0><<<gg, 256, 0, stream>>>(qc, wqb, b_q, Qp);
  gemm_bias<0><<<gg, 256, 0, stream>>>(kc, wkb, b_k, Kp);
  gemm_bias<1><<<gg, 256, 0, stream>>>(vc, wvb, b_v, Vt);
  attn_kernel<<<1024, 256, 0, stream>>>(Qp, Kp, Vt, maskB, Xb);
  gemm_bias<2><<<gg, 256, 0, stream>>>(Xb, wob, b_o, d_out);
}

// Round 5
// 249.256 us; speedup vs baseline: 2.5801x; 1.0781x over previous
//
#include <hip/hip_runtime.h>

typedef __bf16 bf16_t;
typedef __bf16 bf16x4 __attribute__((ext_vector_type(4)));
typedef __bf16 bf16x8 __attribute__((ext_vector_type(8)));
typedef float f32x4 __attribute__((ext_vector_type(4)));
typedef float f32x16 __attribute__((ext_vector_type(16)));
typedef unsigned int uint;
typedef uint uint4v __attribute__((ext_vector_type(4)));

static __device__ __forceinline__ bf16_t f2bf(float f) {
  unsigned u = __builtin_bit_cast(unsigned, f);
  u = (u + 0x7fff + ((u >> 16) & 1)) >> 16;
  unsigned short h = (unsigned short)u;
  return __builtin_bit_cast(bf16_t, h);
}
// v_cvt_pk_bf16_f32: dst.lo = bf16(a), dst.hi = bf16(b)  (T12 recipe)
static __device__ __forceinline__ uint cvt_pk(float a, float b) {
  uint r;
  asm("v_cvt_pk_bf16_f32 %0, %1, %2" : "=v"(r) : "v"(a), "v"(b));
  return r;
}

// ---------------- conversion kernels ----------------
__global__ void cvt3_f2b(const float* __restrict__ a, const float* __restrict__ b,
                         const float* __restrict__ c, bf16_t* __restrict__ oa,
                         bf16_t* __restrict__ ob, bf16_t* __restrict__ oc) {
  int i = blockIdx.x * 256 + threadIdx.x;  // 3 * 2097152
  const float* src = a;
  bf16_t* dst = oa;
  if (i >= 4194304) { src = c; dst = oc; i -= 4194304; }
  else if (i >= 2097152) { src = b; dst = ob; i -= 2097152; }
  const float4 f = reinterpret_cast<const float4*>(src)[i];
  bf16x4 o;
  o[0] = f2bf(f.x); o[1] = f2bf(f.y); o[2] = f2bf(f.z); o[3] = f2bf(f.w);
  reinterpret_cast<bf16x4*>(dst)[i] = o;
}

__global__ void cvt4_f2b(const float* __restrict__ a, const float* __restrict__ b,
                         const float* __restrict__ c, const float* __restrict__ d,
                         bf16_t* __restrict__ oa, bf16_t* __restrict__ ob,
                         bf16_t* __restrict__ oc, bf16_t* __restrict__ od) {
  int i = blockIdx.x * 256 + threadIdx.x;  // 4 * 262144
  const float* src = a;
  bf16_t* dst = oa;
  int w = i >> 18;
  i &= 262143;
  if (w == 1) { src = b; dst = ob; }
  else if (w == 2) { src = c; dst = oc; }
  else if (w == 3) { src = d; dst = od; }
  const float4 f = reinterpret_cast<const float4*>(src)[i];
  bf16x4 o;
  o[0] = f2bf(f.x); o[1] = f2bf(f.y); o[2] = f2bf(f.z); o[3] = f2bf(f.w);
  reinterpret_cast<bf16x4*>(dst)[i] = o;
}

// mask -> packed bits, [t][q] uint32. bit j   = mask[q][32t + (j&3)+8*(j>>2)]
//                                    bit 16+j = mask[q][32t + (j&3)+8*(j>>2)+4]
__global__ void mask_bits_k(const int* __restrict__ m, uint* __restrict__ out) {
  int i = blockIdx.x * 256 + threadIdx.x;  // 131072
  int q = i & 2047, t = i >> 11;
  const int* mrow = m + (size_t)q * 2048 + t * 32;
  uint bits = 0;
#pragma unroll
  for (int j = 0; j < 16; ++j) {
    int r0 = (j & 3) + 8 * (j >> 2);
    bits |= (mrow[r0] ? 1u : 0u) << j;
    bits |= (mrow[r0 + 4] ? 1u : 0u) << (16 + j);
  }
  out[(size_t)t * 2048 + q] = bits;
}

// ---------------- GEMM: C[m,n] = sum_k A[m,k]*Bw[n,k] + bias[n] ----------------
#define GLD_LDS(g, l) \
  __builtin_amdgcn_global_load_lds((const __attribute__((address_space(1))) void*)(g), \
                                   (__attribute__((address_space(3))) void*)(l), 16, 0, 0)

template <int OM>
__global__ __launch_bounds__(256, 2) void gemm_bias(
    const bf16_t* __restrict__ A, const bf16_t* __restrict__ Bw,
    const float* __restrict__ bias, void* __restrict__ Cout) {
  constexpr int K = 1024, N = 1024;
  __shared__ bf16_t As[128 * 32];
  __shared__ bf16_t Bs[128 * 32];
  const int tid = threadIdx.x;
  const int lane = tid & 63;
  const int wave = tid >> 6;
  const int wm = (wave >> 1) * 64, wn = (wave & 1) * 64;
  const int l15 = lane & 15, lhi = lane >> 4;
  const int bm = blockIdx.x, bn = blockIdx.y;
  const int r0 = tid >> 2;
  const int kc = (tid & 3) * 8;
  const bf16_t* ga = A + (size_t)(bm * 128 + r0) * K + kc;
  const bf16_t* gb = Bw + (size_t)(bn * 128 + r0) * K + kc;
  char* ldsA = (char*)As + wave * 1024;
  char* ldsB = (char*)Bs + wave * 1024;
  f32x4 acc[4][4] = {};
  for (int k0 = 0; k0 < K; k0 += 32) {
    __syncthreads();
    GLD_LDS(ga + k0, ldsA);
    GLD_LDS(ga + 64 * K + k0, ldsA + 4096);
    GLD_LDS(gb + k0, ldsB);
    GLD_LDS(gb + 64 * K + k0, ldsB + 4096);
    __syncthreads();
    bf16x8 af[4], bfv[4];
#pragma unroll
    for (int i = 0; i < 4; ++i)
      af[i] = *reinterpret_cast<const bf16x8*>(&As[(wm + i * 16 + l15) * 32 + lhi * 8]);
#pragma unroll
    for (int j = 0; j < 4; ++j)
      bfv[j] = *reinterpret_cast<const bf16x8*>(&Bs[(wn + j * 16 + l15) * 32 + lhi * 8]);
#pragma unroll
    for (int i = 0; i < 4; ++i)
#pragma unroll
      for (int j = 0; j < 4; ++j)
        acc[i][j] = __builtin_amdgcn_mfma_f32_16x16x32_bf16(af[i], bfv[j], acc[i][j], 0, 0, 0);
  }
#pragma unroll
  for (int i = 0; i < 4; ++i) {
#pragma unroll
    for (int j = 0; j < 4; ++j) {
      int n = bn * 128 + wn + j * 16 + l15;
      float bv = bias[n];
#pragma unroll
      for (int r = 0; r < 4; ++r) {
        int m = bm * 128 + wm + i * 16 + lhi * 4 + r;
        float val = acc[i][j][r] + bv;
        if (OM == 0) {
          ((bf16_t*)Cout)[(size_t)m * N + n] = f2bf(val);
        } else if (OM == 1) {
          int b = m >> 11, s = m & 2047;
          ((bf16_t*)Cout)[((size_t)b * 1024 + n) * 2048 + s] = f2bf(val);
        } else {
          ((float*)Cout)[(size_t)m * N + n] = val;
        }
      }
    }
  }
}

// ---------------- flash attention: LDS-staged tiles, 32x32 swapped-operand ----------------
// Grid 1024: blk = qt4*64 + bh  (all 16 q-tiles of one (b,h) land on one XCD).
__global__ __launch_bounds__(256, 4) void attn_kernel(
    const bf16_t* __restrict__ Qp, const bf16_t* __restrict__ Kp,
    const bf16_t* __restrict__ Vt, const uint* __restrict__ maskbits,
    bf16_t* __restrict__ Xb) {
  constexpr int S = 2048, D = 1024;
  constexpr float CS = 0.18033688011112042f;  // 0.125 * log2(e)
  __shared__ __align__(16) bf16_t Ks[2][32][72];  // 64 cols + 8 pad
  __shared__ __align__(16) bf16_t Vs[2][64][40];  // 32 cols + 8 pad
  const int tid = threadIdx.x;
  const int wave = tid >> 6, lane = tid & 63;
  const int l31 = lane & 31, h = lane >> 5;
  const int blk = blockIdx.x;
  const int bh = blk & 63, qt4 = blk >> 6;
  const int b = bh >> 4, hd = bh & 15;
  const int q0 = qt4 * 128 + wave * 32;

  // staging decomposition (256 threads)
  const int rK = tid >> 3, sK = tid & 7;  // K: 32 rows x 8 slots of 16B
  const int rV = tid >> 2, sV = tid & 3;  // V: 64 rows x 4 slots of 16B
  const bf16_t* gK = Kp + (size_t)b * S * D + (size_t)rK * D + hd * 64 + sK * 8;
  const bf16_t* gV = Vt + ((size_t)b * 1024 + hd * 64 + rV) * (size_t)S + sV * 8;

  // Q as B-fragment: col q = l31, rows d = 16c + 8h + j
  const bf16_t* qbase = Qp + (size_t)(b * S + q0 + l31) * D + hd * 64 + h * 8;
  bf16x8 qf[4];
#pragma unroll
  for (int c = 0; c < 4; ++c)
    qf[c] = *reinterpret_cast<const bf16x8*>(qbase + 16 * c);

  const uint* mbase = maskbits + q0 + l31;

  // ones B-fragment for the lsum-via-MFMA trick
  bf16x8 ones;
#pragma unroll
  for (int i = 0; i < 8; ++i) ones[i] = (bf16_t)1.0f;

  f32x16 o0 = {}, o1 = {}, osum = {};
  float mrun = 0.f;  // fixed ref point; rescale only if scores exceed THR

  // prologue: stage tile 0
  {
    bf16x8 k0r = *reinterpret_cast<const bf16x8*>(gK);
    bf16x8 v0r = *reinterpret_cast<const bf16x8*>(gV);
    *reinterpret_cast<bf16x8*>(&Ks[0][rK][sK * 8]) = k0r;
    *reinterpret_cast<bf16x8*>(&Vs[0][rV][sV * 8]) = v0r;
    __syncthreads();
  }

#pragma unroll 2
  for (int t = 0; t < 64; ++t) {
    const int cur = t & 1, nxt = cur ^ 1;
    const bool pf = (t < 63);
    // ---- issue next-tile global loads (hidden under compute) ----
    bf16x8 kreg, vreg;
    if (pf) {
      kreg = *reinterpret_cast<const bf16x8*>(gK + (size_t)(t + 1) * 32 * D);
      vreg = *reinterpret_cast<const bf16x8*>(gV + (t + 1) * 32);
    }
    uint mbc = mbase[t * 2048];
    // ---- QK^T from LDS ----
    f32x16 s = {};
    __builtin_amdgcn_s_setprio(1);
#pragma unroll
    for (int c = 0; c < 4; ++c) {
      bf16x8 kf = *reinterpret_cast<const bf16x8*>(&Ks[cur][l31][h * 8 + 16 * c]);
      s = __builtin_amdgcn_mfma_f32_32x32x16_bf16(kf, qf[c], s, 0, 0, 0);
    }
    __builtin_amdgcn_s_setprio(0);
    // ---- softmax ----
    const uint mbh = mbc >> (h << 4);
    // max via v_max3 (nested fmaxf fuses)
    float a0 = fmaxf(fmaxf(s[0], s[1]), s[2]);
    float a1 = fmaxf(fmaxf(s[3], s[4]), s[5]);
    float a2 = fmaxf(fmaxf(s[6], s[7]), s[8]);
    float a3 = fmaxf(fmaxf(s[9], s[10]), s[11]);
    float a4 = fmaxf(fmaxf(s[12], s[13]), s[14]);
    float b0 = fmaxf(fmaxf(a0, a1), a2);
    float b1 = fmaxf(a3, a4);
    float mt = fmaxf(fmaxf(b0, b1), s[15]);
    mt = fmaxf(mt, __shfl_xor(mt, 32));
    if (!__all(mt - mrun <= 44.36142f)) {  // defer-max safety (never for |s|<~44)
      float mnew = fmaxf(mrun, mt);
      float alpha = __builtin_amdgcn_exp2f((mrun - mnew) * CS);
#pragma unroll
      for (int r = 0; r < 16; ++r) { o0[r] *= alpha; o1[r] *= alpha; osum[r] *= alpha; }
      mrun = mnew;
    }
    const float mc = mrun * CS;
    float p[16];
#pragma unroll
    for (int r = 0; r < 16; ++r) {
      float pv = __builtin_amdgcn_exp2f(__builtin_fmaf(s[r], CS, -mc));
      uint smask = (uint)__builtin_amdgcn_sbfe((int)mbh, r, 1);  // 0 or ~0
      p[r] = __builtin_bit_cast(float, __builtin_bit_cast(uint, pv) & smask);
    }
    // pack p -> bf16 dwords (v_cvt_pk), rearrange into A-fragment via xor-32 exchange
    uint dw[8];
#pragma unroll
    for (int i = 0; i < 8; ++i) dw[i] = cvt_pk(p[2 * i], p[2 * i + 1]);
    uint e0 = (uint)__shfl_xor((int)(h ? dw[0] : dw[2]), 32);
    uint e1 = (uint)__shfl_xor((int)(h ? dw[1] : dw[3]), 32);
    uint e2 = (uint)__shfl_xor((int)(h ? dw[4] : dw[6]), 32);
    uint e3 = (uint)__shfl_xor((int)(h ? dw[5] : dw[7]), 32);
    uint4v ua0 = {h ? e0 : dw[0], h ? e1 : dw[1], h ? dw[2] : e0, h ? dw[3] : e1};
    uint4v ua1 = {h ? e2 : dw[4], h ? e3 : dw[5], h ? dw[6] : e2, h ? dw[7] : e3};
    bf16x8 pa0 = __builtin_bit_cast(bf16x8, ua0);
    bf16x8 pa1 = __builtin_bit_cast(bf16x8, ua1);
    // ---- PV + row-sum from LDS / MFMA ----
    {
      bf16x8 v00 = *reinterpret_cast<const bf16x8*>(&Vs[cur][l31][h * 8]);
      bf16x8 v01 = *reinterpret_cast<const bf16x8*>(&Vs[cur][l31][16 + h * 8]);
      bf16x8 v10 = *reinterpret_cast<const bf16x8*>(&Vs[cur][32 + l31][h * 8]);
      bf16x8 v11 = *reinterpret_cast<const bf16x8*>(&Vs[cur][32 + l31][16 + h * 8]);
      __builtin_amdgcn_s_setprio(1);
      o0 = __builtin_amdgcn_mfma_f32_32x32x16_bf16(pa0, v00, o0, 0, 0, 0);
      o0 = __builtin_amdgcn_mfma_f32_32x32x16_bf16(pa1, v01, o0, 0, 0, 0);
      o1 = __builtin_amdgcn_mfma_f32_32x32x16_bf16(pa0, v10, o1, 0, 0, 0);
      o1 = __builtin_amdgcn_mfma_f32_32x32x16_bf16(pa1, v11, o1, 0, 0, 0);
      osum = __builtin_amdgcn_mfma_f32_32x32x16_bf16(pa0, ones, osum, 0, 0, 0);
      osum = __builtin_amdgcn_mfma_f32_32x32x16_bf16(pa1, ones, osum, 0, 0, 0);
      __builtin_amdgcn_s_setprio(0);
    }
    // ---- write staged tile t+1, one barrier per tile ----
    if (pf) {
      *reinterpret_cast<bf16x8*>(&Ks[nxt][rK][sK * 8]) = kreg;
      *reinterpret_cast<bf16x8*>(&Vs[nxt][rV][sV * 8]) = vreg;
      __syncthreads();
    }
  }
  // epilogue: osum[r] holds the row-sum for exactly o0[r]/o1[r]'s q-row
  bf16_t* xrow = Xb + (size_t)(b * S + q0) * D + hd * 64 + l31;
#pragma unroll
  for (int r = 0; r < 16; ++r) {
    int qrow = (r & 3) + 8 * (r >> 2) + 4 * h;
    float lr = __builtin_amdgcn_rcpf(osum[r]);
    xrow[(size_t)qrow * D] = f2bf(o0[r] * lr);
    xrow[(size_t)qrow * D + 32] = f2bf(o1[r] * lr);
  }
}

// ---------------- launch ----------------
extern "C" void kernel_launch(void* const* d_in, const int* in_sizes, int n_in,
                              void* d_out, int out_size, void* d_ws, size_t ws_size,
                              hipStream_t stream) {
  const float* q = (const float*)d_in[0];
  const float* k = (const float*)d_in[1];
  const float* v = (const float*)d_in[2];
  const int* mask = (const int*)d_in[3];
  const float* w_q = (const float*)d_in[4];
  const float* b_q = (const float*)d_in[5];
  const float* w_k = (const float*)d_in[6];
  const float* b_k = (const float*)d_in[7];
  const float* w_v = (const float*)d_in[8];
  const float* b_v = (const float*)d_in[9];
  const float* w_o = (const float*)d_in[10];
  const float* b_o = (const float*)d_in[11];

  char* ws = (char*)d_ws;
  const size_t SZ = (size_t)8192 * 1024 * 2;
  bf16_t* qc = (bf16_t*)(ws + 0 * SZ);
  bf16_t* kc = (bf16_t*)(ws + 1 * SZ);
  bf16_t* vc = (bf16_t*)(ws + 2 * SZ);
  bf16_t* Qp = (bf16_t*)(ws + 3 * SZ);
  bf16_t* Kp = (bf16_t*)(ws + 4 * SZ);
  bf16_t* Vt = (bf16_t*)(ws + 5 * SZ);
  bf16_t* Xb = (bf16_t*)(ws + 6 * SZ);
  uint* maskB = (uint*)(ws + 7 * SZ);  // 512 KiB packed mask bits
  bf16_t* wqb = (bf16_t*)(ws + 7 * SZ + 8388608);
  bf16_t* wkb = wqb + 1048576;
  bf16_t* wvb = wkb + 1048576;
  bf16_t* wob = wvb + 1048576;

  cvt3_f2b<<<24576, 256, 0, stream>>>(q, k, v, qc, kc, vc);
  cvt4_f2b<<<4096, 256, 0, stream>>>(w_q, w_k, w_v, w_o, wqb, wkb, wvb, wob);
  mask_bits_k<<<512, 256, 0, stream>>>(mask, maskB);

  dim3 gg(64, 8);
  gemm_bias<0><<<gg, 256, 0, stream>>>(qc, wqb, b_q, Qp);
  gemm_bias<0><<<gg, 256, 0, stream>>>(kc, wkb, b_k, Kp);
  gemm_bias<1><<<gg, 256, 0, stream>>>(vc, wvb, b_v, Vt);
  attn_kernel<<<1024, 256, 0, stream>>>(Qp, Kp, Vt, maskB, Xb);
  gemm_bias<2><<<gg, 256, 0, stream>>>(Xb, wob, b_o, d_out);
}